// Round 15
// baseline (100.592 us; speedup 1.0000x reference)
//
#include <hip/hip_runtime.h>
#include <stdint.h>

// SNN XOR net — correct recipe (R14), optimized (R15).
// Recipe (bit-exact, verified absmax=0.0):
//   cur  = (x0*w10) + (x1*w11)                 // no fma: two rounded products
//   m    = fmaf(0.9f, m, cur); m = m - s_prev; // fused mul-add, separate sub
//   s    = (m > 1.0f)                          // spike; reused as next reset
//   outv = ((s0*w20 + s1*w21) + s2*w22) + s3*w23  // exact products, seq sum
// R15 changes (arithmetic identical):
//   VEC 4->2: 2048 blocks -> 8 blocks/CU = 32 waves/CU (full occupancy; was 16)
//   spike-carry: s stored once per update, reused as r (kills a cmp+select/step)
//   __launch_bounds__(256,8): target 8 waves/SIMD.
// Roofline: 84 MB writes + 8.4 MB reads ~ 15 us at 6.3 TB/s; VALU ~ 8 us.

constexpr int T_STEPS = 20;
constexpr int H = 4;
constexpr int VEC = 2;   // 2 batch elements/thread: one float4 x-load, float2 stores

__global__ __launch_bounds__(256, 8) void snn_r15_kernel(
    const float* __restrict__ x,    // f32 [B,2]
    const float* __restrict__ w1,   // f32 [4,2] row-major
    const float* __restrict__ w2,   // f32 [1,4]
    float* __restrict__ out,        // f32 [T,B]
    int B)
{
#pragma clang fp contract(off)
    const int tid = blockIdx.x * blockDim.x + threadIdx.x;
    if (tid * VEC >= B) return;

    float w1r[H][2], w2r[H];
#pragma unroll
    for (int h = 0; h < H; ++h) {
        w1r[h][0] = w1[2 * h];
        w1r[h][1] = w1[2 * h + 1];
        w2r[h]    = w2[h];
    }

    // 2 elements x 2 features = one exact float4 load.
    const float4 xq = reinterpret_cast<const float4*>(x)[tid];
    const float xv[VEC][2] = {{xq.x, xq.y}, {xq.z, xq.w}};

    float cur[VEC][H], m1[VEC][H], s1[VEC][H], m2[VEC], s2[VEC];
#pragma unroll
    for (int l = 0; l < VEC; ++l) {
#pragma unroll
        for (int h = 0; h < H; ++h) {
            // nofma dot: round both products, then one add
            cur[l][h] = (xv[l][0] * w1r[h][0]) + (xv[l][1] * w1r[h][1]);
            m1[l][h] = 0.0f;
            s1[l][h] = 0.0f;
        }
        m2[l] = 0.0f;
        s2[l] = 0.0f;
    }

#pragma unroll
    for (int t = 0; t < T_STEPS; ++t) {
        float2 o;
        float* op = reinterpret_cast<float*>(&o);
#pragma unroll
        for (int l = 0; l < VEC; ++l) {
#pragma unroll
            for (int h = 0; h < H; ++h) {
                float m = fmaf(0.9f, m1[l][h], cur[l][h]);  // fused mul-add
                m = m - s1[l][h];                           // separate subtract
                m1[l][h] = m;
                s1[l][h] = (m > 1.0f) ? 1.0f : 0.0f;        // spike & next reset
            }
            // L2 dot: products exact (s in {0,1}), sequential sum
            const float outv = ((s1[l][0] * w2r[0] + s1[l][1] * w2r[1])
                                + s1[l][2] * w2r[2]) + s1[l][3] * w2r[3];
            float m = fmaf(0.9f, m2[l], outv);
            m = m - s2[l];
            m2[l] = m;
            const float s = (m > 1.0f) ? 1.0f : 0.0f;
            s2[l] = s;
            op[l] = s;
        }
        // out[t*B + 2*tid]: 8 B/lane, 512 B/wave contiguous -> fully coalesced.
        reinterpret_cast<float2*>(out + (size_t)t * B)[tid] = o;
    }
}

extern "C" void kernel_launch(void* const* d_in, const int* in_sizes, int n_in,
                              void* d_out, int out_size, void* d_ws, size_t ws_size,
                              hipStream_t stream) {
    const float* x  = (const float*)d_in[0];
    const float* w1 = (const float*)d_in[1];
    const float* w2 = (const float*)d_in[2];
    float* out = (float*)d_out;
    const int B = in_sizes[0] / 2;          // 1,048,576
    const int n_thr = B / VEC;              // 524,288 threads = 2048 blocks
    const int threads = 256;
    snn_r15_kernel<<<(n_thr + threads - 1) / threads, threads, 0, stream>>>(x, w1, w2, out, B);
}